// Round 1
// baseline (366.781 us; speedup 1.0000x reference)
//
#include <hip/hip_runtime.h>
#include <hip/hip_bf16.h>

// 4-D "same" conv as implicit GEMM on bf16 MFMA.
//   M = COUT = 16, N = 16 positions/wave, K = 648 -> pad 672 (21 chunks of 32).
//   Each wave processes the SAME 16 positions for 4 BATCHES:
//   tap decomposition/validity/q computed once per chunk, shared by 4 gathers+MFMAs.
// Prepass 1: weights -> A-frag order Wpack[chunk][lane][8] bf16 (zero-pad k>=648).
// Prepass 2: x (B,CIN,SP) fp32 -> xT (B,SP,CIN) bf16 via HW packed cvt
//            (__float22bfloat162_rn), 2 positions/thread.
// R1 change: XCD-aware chunked blockIdx swizzle in conv4d_mfma (bijective:
//            10368 % 8 == 0) so neighboring position-tiles share an XCD L2 —
//            targets the ~27x cross-wave gather re-reads of xT.

#define SDIM  24
#define SP    (SDIM * SDIM * SDIM * SDIM)   // 331776
#define CIN   8
#define COUT  16
#define BATCH 8
#define KW    648                            // 81 * CIN
#define NCHUNK 21                            // ceil(648/32)
#define NB    4                              // batches per wave
#define PTILES (SP / 16)                     // 20736 position tiles
#define NBLOCKS ((BATCH / NB) * PTILES / 4)  // 10368
#define NXCD  8
#define CPX   (NBLOCKS / NXCD)               // 1296 (exact)

#define ZERO_OFF 0
#define WPK_OFF  256
#define XT_OFF   32768
#define XT_BYTES ((size_t)BATCH * SP * CIN * 2)          // 42,467,328
#define WS_NEEDED (XT_OFF + XT_BYTES)

typedef __attribute__((ext_vector_type(8))) short short8;   // 8 bf16 = 4 VGPRs
typedef __attribute__((ext_vector_type(4))) float f32x4;

static __device__ __forceinline__ unsigned short f2bf(float f) {
    unsigned u = __builtin_bit_cast(unsigned, f);
    u = (u + 0x7fffu + ((u >> 16) & 1u)) >> 16;          // RNE
    return (unsigned short)u;
}

// ---------- prepass 1: pack weights + zero slot ----------
__global__ __launch_bounds__(256) void pack_weights(
    const float* __restrict__ w, unsigned char* __restrict__ ws)
{
    int t = blockIdx.x * 256 + threadIdx.x;              // 0..1535
    if (t == 1344) {                                     // zero slot (16 B)
        short8 z = {0,0,0,0,0,0,0,0};
        *(short8*)(ws + ZERO_OFF) = z;
    }
    if (t >= NCHUNK * 64) return;
    int chunk = t >> 6;
    int lane  = t & 63;
    int m     = lane & 15;
    int quad  = lane >> 4;
    short8 pk;
    #pragma unroll
    for (int j = 0; j < 8; ++j) {
        int k = chunk * 32 + quad * 8 + j;
        float f = (k < KW) ? w[m * KW + k] : 0.0f;
        pk[j] = (short)f2bf(f);
    }
    ((short8*)(ws + WPK_OFF))[chunk * 64 + lane] = pk;
}

// ---------- prepass 2: x (B,CIN,SP) fp32 -> xT (B,SP,CIN) bf16 ----------
// 2 positions per thread; packed HW bf16 convert.
__global__ __launch_bounds__(256) void transpose_x(
    const float* __restrict__ x, unsigned char* __restrict__ ws)
{
    int idx = blockIdx.x * 256 + threadIdx.x;            // pair index
    int b  = idx / (SP / 2);
    int pp = idx - b * (SP / 2);
    int p  = pp * 2;
    const float* xb = x + (size_t)b * CIN * SP + p;

    float2 v[CIN];
    #pragma unroll
    for (int c = 0; c < CIN; ++c)
        v[c] = *(const float2*)(xb + (size_t)c * SP);

    union { __hip_bfloat162 h2[4]; short8 s8; } u0, u1;
    #pragma unroll
    for (int i = 0; i < 4; ++i) {
        float2 a = make_float2(v[2 * i].x, v[2 * i + 1].x);   // position p
        float2 bq = make_float2(v[2 * i].y, v[2 * i + 1].y);  // position p+1
        u0.h2[i] = __float22bfloat162_rn(a);
        u1.h2[i] = __float22bfloat162_rn(bq);
    }
    short8* dst = (short8*)(ws + XT_OFF) + ((size_t)b * SP + p);
    dst[0] = u0.s8;
    dst[1] = u1.s8;
}

// ---------- main: implicit GEMM, 4 batches per wave ----------
__global__ __launch_bounds__(256) void conv4d_mfma(
    const unsigned char* __restrict__ ws,
    const float* __restrict__ bias,
    float* __restrict__ out)
{
    const int lane = threadIdx.x & 63;
    const int wave = threadIdx.x >> 6;
    const int col  = lane & 15;
    const int quad = lane >> 4;

    // XCD-aware chunked swizzle (bijective: NBLOCKS % 8 == 0).
    // Default dispatch puts blockIdx b on XCD b%8; remap so each XCD works a
    // CONTIGUOUS pt-range -> cross-wave tap re-reads hit that XCD's L2.
    int bid = blockIdx.x;
    bid = (bid & (NXCD - 1)) * CPX + (bid >> 3);

    int W = bid * 4 + wave;                              // 0..41471
    W = __builtin_amdgcn_readfirstlane(W);               // wave-uniform -> SGPR
    const int pt = W % PTILES;                           // position tile
    const int g  = W / PTILES;                           // batch group 0..1

    const int p = pt * 16 + col;
    int r = p;
    const int p4 = r % SDIM; r /= SDIM;
    const int p3 = r % SDIM; r /= SDIM;
    const int p2 = r % SDIM;
    const int p1 = r / SDIM;

    const short8* wpk  = (const short8*)(ws + WPK_OFF);
    const short8* xT   = (const short8*)(ws + XT_OFF);
    const short8* zslt = (const short8*)(ws + ZERO_OFF);

    const short8* xb[NB];
    #pragma unroll
    for (int t = 0; t < NB; ++t)
        xb[t] = xT + (size_t)(g * NB + t) * SP;

    f32x4 acc[NB];
    #pragma unroll
    for (int t = 0; t < NB; ++t) acc[t] = (f32x4){0.f, 0.f, 0.f, 0.f};

    #pragma unroll
    for (int c = 0; c < NCHUNK; ++c) {
        short8 afrag = wpk[c * 64 + lane];

        int tap = c * 4 + quad;
        int k1 = tap / 27; int rem = tap - k1 * 27;
        int k2 = rem / 9;  rem -= k2 * 9;
        int k3 = rem / 3;
        int k4 = rem - k3 * 3;
        int q1 = p1 + k1 - 1, q2 = p2 + k2 - 1, q3 = p3 + k3 - 1, q4 = p4 + k4 - 1;
        bool valid = ((unsigned)q1 < (unsigned)SDIM) & ((unsigned)q2 < (unsigned)SDIM) &
                     ((unsigned)q3 < (unsigned)SDIM) & ((unsigned)q4 < (unsigned)SDIM);
        int q = ((q1 * SDIM + q2) * SDIM + q3) * SDIM + q4;

        short8 bf[NB];
        #pragma unroll
        for (int t = 0; t < NB; ++t) {
            const short8* src = valid ? (xb[t] + q) : zslt;
            bf[t] = *src;
        }
        #pragma unroll
        for (int t = 0; t < NB; ++t)
            acc[t] = __builtin_amdgcn_mfma_f32_16x16x32_bf16(afrag, bf[t], acc[t], 0, 0, 0);
    }

    // epilogue: D[row=quad*4+reg][col] -> out[b][row][p] ; add bias
    f32x4 b4 = *(const f32x4*)(bias + quad * 4);
    #pragma unroll
    for (int t = 0; t < NB; ++t) {
        float* obase = out + ((size_t)(g * NB + t) * COUT + quad * 4) * SP + p;
        #pragma unroll
        for (int reg = 0; reg < 4; ++reg)
            obase[(size_t)reg * SP] = acc[t][reg] + b4[reg];
    }
}

// ---------- fallback (direct fp32) if ws too small ----------
__global__ __launch_bounds__(256) void conv4d_direct(
    const float* __restrict__ x, const float* __restrict__ w,
    const float* __restrict__ bias, float* __restrict__ out)
{
    int t = blockIdx.x * blockDim.x + threadIdx.x;
    int b = t / SP;
    int p = t - b * SP;
    int p4 = p % SDIM; int tmp = p / SDIM;
    int p3 = tmp % SDIM; tmp /= SDIM;
    int p2 = tmp % SDIM; int p1 = tmp / SDIM;
    float acc[COUT];
    #pragma unroll
    for (int o = 0; o < COUT; ++o) acc[o] = bias[o];
    const float* xb = x + (size_t)b * CIN * SP;
    for (int k1 = 0; k1 < 3; ++k1) {
        unsigned q1 = (unsigned)(p1 + k1 - 1); if (q1 >= SDIM) continue;
        for (int k2 = 0; k2 < 3; ++k2) {
            unsigned q2 = (unsigned)(p2 + k2 - 1); if (q2 >= SDIM) continue;
            for (int k3 = 0; k3 < 3; ++k3) {
                unsigned q3 = (unsigned)(p3 + k3 - 1); if (q3 >= SDIM) continue;
                int base123 = (((int)q1 * SDIM + (int)q2) * SDIM + (int)q3) * SDIM;
                int kf = ((k1 * 3 + k2) * 3 + k3) * 3;
                for (int k4 = 0; k4 < 3; ++k4) {
                    unsigned q4 = (unsigned)(p4 + k4 - 1); if (q4 >= SDIM) continue;
                    int q = base123 + (int)q4;
                    float xv[CIN];
                    #pragma unroll
                    for (int c = 0; c < CIN; ++c) xv[c] = xb[c * SP + q];
                    const float* wp = w + (kf + k4) * CIN;
                    #pragma unroll
                    for (int o = 0; o < COUT; ++o)
                        #pragma unroll
                        for (int c = 0; c < CIN; ++c)
                            acc[o] = fmaf(xv[c], wp[o * KW + c], acc[o]);
                }
            }
        }
    }
    float* ob = out + (size_t)b * COUT * SP + p;
    #pragma unroll
    for (int o = 0; o < COUT; ++o) ob[o * SP] = acc[o];
}

extern "C" void kernel_launch(void* const* d_in, const int* in_sizes, int n_in,
                              void* d_out, int out_size, void* d_ws, size_t ws_size,
                              hipStream_t stream)
{
    const float* x    = (const float*)d_in[0];
    const float* w    = (const float*)d_in[1];
    const float* bias = (const float*)d_in[2];
    float* out        = (float*)d_out;

    if (ws_size < WS_NEEDED) {                           // insurance
        const int total = BATCH * SP;
        hipLaunchKernelGGL(conv4d_direct, dim3(total / 256), dim3(256), 0, stream,
                           x, w, bias, out);
        return;
    }

    unsigned char* ws = (unsigned char*)d_ws;

    hipLaunchKernelGGL(pack_weights, dim3(6), dim3(256), 0, stream, w, ws);

    const int pair_total = BATCH * SP / 2;               // 1,327,104
    hipLaunchKernelGGL(transpose_x, dim3(pair_total / 256), dim3(256), 0, stream, x, ws);

    hipLaunchKernelGGL(conv4d_mfma, dim3(NBLOCKS), dim3(256), 0, stream,
                       (const unsigned char*)ws, bias, out);
}

// Round 3
// 350.330 us; speedup vs baseline: 1.0470x; 1.0470x over previous
//
#include <hip/hip_runtime.h>
#include <hip/hip_bf16.h>

// 4-D "same" conv as implicit GEMM on bf16 MFMA.
//   M = COUT = 16, N = 16 positions/wave, K = 648 -> pad 672 (21 chunks of 32).
//   Each wave processes the SAME 16 positions for 4 BATCHES.
// R2/R3: ZERO-PADDED xT (26^4 spatial halo) kills ALL per-chunk validity
//   VALU (compares/cndmask/q-reconstruction). Inner loop per chunk is now:
//   ds_read_b128 (A-frag from LDS) + ds_read_b32 (tap delta from LDS, quad-
//   broadcast) + v_add (voff) + 4x global_load_dwordx4 + 4x MFMA.
//   (R3 = R2 resubmitted unchanged after infra failure; R2 was never run.)
// Paths: padded-MFMA (ws >= 58.5 MB) -> old unpadded-MFMA (ws >= 42.5 MB)
//        -> direct fp32 (insurance).

#define SDIM  24
#define SP    (SDIM * SDIM * SDIM * SDIM)   // 331776
#define PD    26
#define SPPAD (PD * PD * PD * PD)            // 456976
#define CIN   8
#define COUT  16
#define BATCH 8
#define KW    648                            // 81 * CIN
#define NCHUNK 21                            // ceil(648/32)
#define NB    4                              // batches per wave
#define PTILES (SP / 16)                     // 20736 position tiles
#define NBLOCKS ((BATCH / NB) * PTILES / 4)  // 10368

#define ZERO_OFF 0
#define WPK_OFF  256
#define XT_OFF   32768
#define XT_BYTES  ((size_t)BATCH * SP * CIN * 2)          // 42,467,328
#define XTP_BYTES ((size_t)BATCH * SPPAD * CIN * 2)       // 58,492,928
#define WS_NEEDED_OLD (XT_OFF + XT_BYTES)
#define WS_NEEDED_PAD (XT_OFF + XTP_BYTES)

#define ZTOTAL ((size_t)BATCH * SPPAD)       // short8 slots to zero: 3,655,808
#define ZBLOCKS 14281                        // ceil(ZTOTAL/256)

typedef __attribute__((ext_vector_type(8))) short short8;   // 8 bf16 = 4 VGPRs
typedef __attribute__((ext_vector_type(4))) float f32x4;

static __device__ __forceinline__ unsigned short f2bf(float f) {
    unsigned u = __builtin_bit_cast(unsigned, f);
    u = (u + 0x7fffu + ((u >> 16) & 1u)) >> 16;          // RNE
    return (unsigned short)u;
}

// ---------- prepass (padded path): zero xTp + pack weights, one launch ----------
__global__ __launch_bounds__(256) void prep0_pad(
    const float* __restrict__ w, unsigned char* __restrict__ ws)
{
    if (blockIdx.x < ZBLOCKS) {                          // zero-fill xTp
        size_t i = (size_t)blockIdx.x * 256 + threadIdx.x;
        if (i < ZTOTAL) {
            short8 z = {0, 0, 0, 0, 0, 0, 0, 0};
            ((short8*)(ws + XT_OFF))[i] = z;
        }
        return;
    }
    int t = (blockIdx.x - ZBLOCKS) * 256 + threadIdx.x;  // weight pack
    if (t >= NCHUNK * 64) return;
    int chunk = t >> 6;
    int lane  = t & 63;
    int m     = lane & 15;
    int quad  = lane >> 4;
    short8 pk;
    #pragma unroll
    for (int j = 0; j < 8; ++j) {
        int k = chunk * 32 + quad * 8 + j;
        float f = (k < KW) ? w[m * KW + k] : 0.0f;
        pk[j] = (short)f2bf(f);
    }
    ((short8*)(ws + WPK_OFF))[chunk * 64 + lane] = pk;
}

// ---------- prepass (padded path): x (B,CIN,SP) fp32 -> xTp (B,26^4,CIN) bf16 ----------
// 4 positions/thread (float4 loads, 64 B contiguous store into padded row).
__global__ __launch_bounds__(256) void transpose_xp(
    const float* __restrict__ x, unsigned char* __restrict__ ws)
{
    int idx = blockIdx.x * 256 + threadIdx.x;            // 0 .. B*SP/4-1
    int b  = idx / (SP / 4);
    int pq = idx - b * (SP / 4);
    int p  = pq * 4;                                     // p4 % 4 == 0 (24%4==0)
    const float* xb = x + (size_t)b * CIN * SP + p;

    float4 v[CIN];
    #pragma unroll
    for (int c = 0; c < CIN; ++c)
        v[c] = *(const float4*)(xb + (size_t)c * SP);

    union { __hip_bfloat162 h2[4]; short8 s8; } u[4];
    #pragma unroll
    for (int j = 0; j < 4; ++j) {
        #pragma unroll
        for (int i = 0; i < 4; ++i) {
            float a0 = (&v[2 * i].x)[j];
            float a1 = (&v[2 * i + 1].x)[j];
            u[j].h2[i] = __float22bfloat162_rn(make_float2(a0, a1));
        }
    }

    int r = p;
    const int p4 = r % SDIM; r /= SDIM;
    const int p3 = r % SDIM; r /= SDIM;
    const int p2 = r % SDIM;
    const int p1 = r / SDIM;
    int qp = (((p1 + 1) * PD + (p2 + 1)) * PD + (p3 + 1)) * PD + (p4 + 1);

    short8* dst = (short8*)(ws + XT_OFF) + (size_t)b * SPPAD + qp;
    #pragma unroll
    for (int j = 0; j < 4; ++j) dst[j] = u[j].s8;
}

// ---------- main (padded): implicit GEMM, no validity logic ----------
__global__ __launch_bounds__(256) void conv4d_mfma_pad(
    const unsigned char* __restrict__ ws,
    const float* __restrict__ bias,
    float* __restrict__ out)
{
    __shared__ int    s_delta[96];            // 84 tap byte-deltas
    __shared__ short8 s_w[NCHUNK * 64];       // 21504 B weight pack

    const int tid  = threadIdx.x;
    const int lane = tid & 63;
    const int wave = tid >> 6;
    const int col  = lane & 15;
    const int quad = lane >> 4;

    // cooperative LDS fill
    const short8* wpk = (const short8*)(ws + WPK_OFF);
    for (int t = tid; t < NCHUNK * 64; t += 256) s_w[t] = wpk[t];
    if (tid < 84) {
        int k1 = tid / 27, rem = tid - k1 * 27;
        int k2 = rem / 9;  rem -= k2 * 9;
        int k3 = rem / 3;
        int k4 = rem - k3 * 3;
        s_delta[tid] = (k1 * (PD * PD * PD) + k2 * (PD * PD) + k3 * PD + k4) * 16;
    }
    __syncthreads();

    int W = blockIdx.x * 4 + wave;                       // 0..41471
    W = __builtin_amdgcn_readfirstlane(W);               // wave-uniform -> SGPR
    const int pt = W % PTILES;                           // position tile
    const int g  = W / PTILES;                           // batch group 0..1

    const int p = pt * 16 + col;
    int r = p;
    const int p4 = r % SDIM; r /= SDIM;
    const int p3 = r % SDIM; r /= SDIM;
    const int p2 = r % SDIM;
    const int p1 = r / SDIM;
    // base byte-offset in padded space (k=0 tap maps p_i -> qp_i = p_i)
    const int pidx16 = (((p1 * PD + p2) * PD + p3) * PD + p4) * 16;

    const unsigned char* xbase[NB];
    #pragma unroll
    for (int t = 0; t < NB; ++t)
        xbase[t] = ws + XT_OFF + (size_t)(g * NB + t) * SPPAD * 16;

    f32x4 acc[NB];
    #pragma unroll
    for (int t = 0; t < NB; ++t) acc[t] = (f32x4){0.f, 0.f, 0.f, 0.f};

    #pragma unroll
    for (int c = 0; c < NCHUNK; ++c) {
        short8 afrag = s_w[c * 64 + lane];               // ds_read_b128
        int voff = pidx16 + s_delta[c * 4 + quad];       // ds_read_b32 + v_add

        short8 bf[NB];
        #pragma unroll
        for (int t = 0; t < NB; ++t)
            bf[t] = *(const short8*)(xbase[t] + voff);   // global_load_dwordx4
        #pragma unroll
        for (int t = 0; t < NB; ++t)
            acc[t] = __builtin_amdgcn_mfma_f32_16x16x32_bf16(afrag, bf[t], acc[t], 0, 0, 0);
    }

    // epilogue: D[row=quad*4+reg][col] -> out[b][row][p] ; add bias
    f32x4 b4 = *(const f32x4*)(bias + quad * 4);
    #pragma unroll
    for (int t = 0; t < NB; ++t) {
        float* obase = out + ((size_t)(g * NB + t) * COUT + quad * 4) * SP + p;
        #pragma unroll
        for (int reg = 0; reg < 4; ++reg)
            obase[(size_t)reg * SP] = acc[t][reg] + b4[reg];
    }
}

// ================= old (unpadded) path — middle fallback =================

__global__ __launch_bounds__(256) void pack_weights(
    const float* __restrict__ w, unsigned char* __restrict__ ws)
{
    int t = blockIdx.x * 256 + threadIdx.x;              // 0..1535
    if (t == 1344) {                                     // zero slot (16 B)
        short8 z = {0,0,0,0,0,0,0,0};
        *(short8*)(ws + ZERO_OFF) = z;
    }
    if (t >= NCHUNK * 64) return;
    int chunk = t >> 6;
    int lane  = t & 63;
    int m     = lane & 15;
    int quad  = lane >> 4;
    short8 pk;
    #pragma unroll
    for (int j = 0; j < 8; ++j) {
        int k = chunk * 32 + quad * 8 + j;
        float f = (k < KW) ? w[m * KW + k] : 0.0f;
        pk[j] = (short)f2bf(f);
    }
    ((short8*)(ws + WPK_OFF))[chunk * 64 + lane] = pk;
}

__global__ __launch_bounds__(256) void transpose_x(
    const float* __restrict__ x, unsigned char* __restrict__ ws)
{
    int idx = blockIdx.x * 256 + threadIdx.x;            // pair index
    int b  = idx / (SP / 2);
    int pp = idx - b * (SP / 2);
    int p  = pp * 2;
    const float* xb = x + (size_t)b * CIN * SP + p;

    float2 v[CIN];
    #pragma unroll
    for (int c = 0; c < CIN; ++c)
        v[c] = *(const float2*)(xb + (size_t)c * SP);

    union { __hip_bfloat162 h2[4]; short8 s8; } u0, u1;
    #pragma unroll
    for (int i = 0; i < 4; ++i) {
        float2 a = make_float2(v[2 * i].x, v[2 * i + 1].x);
        float2 bq = make_float2(v[2 * i].y, v[2 * i + 1].y);
        u0.h2[i] = __float22bfloat162_rn(a);
        u1.h2[i] = __float22bfloat162_rn(bq);
    }
    short8* dst = (short8*)(ws + XT_OFF) + ((size_t)b * SP + p);
    dst[0] = u0.s8;
    dst[1] = u1.s8;
}

__global__ __launch_bounds__(256) void conv4d_mfma(
    const unsigned char* __restrict__ ws,
    const float* __restrict__ bias,
    float* __restrict__ out)
{
    const int lane = threadIdx.x & 63;
    const int wave = threadIdx.x >> 6;
    const int col  = lane & 15;
    const int quad = lane >> 4;

    int W = blockIdx.x * 4 + wave;
    W = __builtin_amdgcn_readfirstlane(W);
    const int pt = W % PTILES;
    const int g  = W / PTILES;

    const int p = pt * 16 + col;
    int r = p;
    const int p4 = r % SDIM; r /= SDIM;
    const int p3 = r % SDIM; r /= SDIM;
    const int p2 = r % SDIM;
    const int p1 = r / SDIM;

    const short8* wpk  = (const short8*)(ws + WPK_OFF);
    const short8* xT   = (const short8*)(ws + XT_OFF);
    const short8* zslt = (const short8*)(ws + ZERO_OFF);

    const short8* xb[NB];
    #pragma unroll
    for (int t = 0; t < NB; ++t)
        xb[t] = xT + (size_t)(g * NB + t) * SP;

    f32x4 acc[NB];
    #pragma unroll
    for (int t = 0; t < NB; ++t) acc[t] = (f32x4){0.f, 0.f, 0.f, 0.f};

    #pragma unroll
    for (int c = 0; c < NCHUNK; ++c) {
        short8 afrag = wpk[c * 64 + lane];

        int tap = c * 4 + quad;
        int k1 = tap / 27; int rem = tap - k1 * 27;
        int k2 = rem / 9;  rem -= k2 * 9;
        int k3 = rem / 3;
        int k4 = rem - k3 * 3;
        int q1 = p1 + k1 - 1, q2 = p2 + k2 - 1, q3 = p3 + k3 - 1, q4 = p4 + k4 - 1;
        bool valid = ((unsigned)q1 < (unsigned)SDIM) & ((unsigned)q2 < (unsigned)SDIM) &
                     ((unsigned)q3 < (unsigned)SDIM) & ((unsigned)q4 < (unsigned)SDIM);
        int q = ((q1 * SDIM + q2) * SDIM + q3) * SDIM + q4;

        short8 bf[NB];
        #pragma unroll
        for (int t = 0; t < NB; ++t) {
            const short8* src = valid ? (xb[t] + q) : zslt;
            bf[t] = *src;
        }
        #pragma unroll
        for (int t = 0; t < NB; ++t)
            acc[t] = __builtin_amdgcn_mfma_f32_16x16x32_bf16(afrag, bf[t], acc[t], 0, 0, 0);
    }

    f32x4 b4 = *(const f32x4*)(bias + quad * 4);
    #pragma unroll
    for (int t = 0; t < NB; ++t) {
        float* obase = out + ((size_t)(g * NB + t) * COUT + quad * 4) * SP + p;
        #pragma unroll
        for (int reg = 0; reg < 4; ++reg)
            obase[(size_t)reg * SP] = acc[t][reg] + b4[reg];
    }
}

// ---------- fallback (direct fp32) if ws too small ----------
__global__ __launch_bounds__(256) void conv4d_direct(
    const float* __restrict__ x, const float* __restrict__ w,
    const float* __restrict__ bias, float* __restrict__ out)
{
    int t = blockIdx.x * blockDim.x + threadIdx.x;
    int b = t / SP;
    int p = t - b * SP;
    int p4 = p % SDIM; int tmp = p / SDIM;
    int p3 = tmp % SDIM; tmp /= SDIM;
    int p2 = tmp % SDIM; int p1 = tmp / SDIM;
    float acc[COUT];
    #pragma unroll
    for (int o = 0; o < COUT; ++o) acc[o] = bias[o];
    const float* xb = x + (size_t)b * CIN * SP;
    for (int k1 = 0; k1 < 3; ++k1) {
        unsigned q1 = (unsigned)(p1 + k1 - 1); if (q1 >= SDIM) continue;
        for (int k2 = 0; k2 < 3; ++k2) {
            unsigned q2 = (unsigned)(p2 + k2 - 1); if (q2 >= SDIM) continue;
            for (int k3 = 0; k3 < 3; ++k3) {
                unsigned q3 = (unsigned)(p3 + k3 - 1); if (q3 >= SDIM) continue;
                int base123 = (((int)q1 * SDIM + (int)q2) * SDIM + (int)q3) * SDIM;
                int kf = ((k1 * 3 + k2) * 3 + k3) * 3;
                for (int k4 = 0; k4 < 3; ++k4) {
                    unsigned q4 = (unsigned)(p4 + k4 - 1); if (q4 >= SDIM) continue;
                    int q = base123 + (int)q4;
                    float xv[CIN];
                    #pragma unroll
                    for (int c = 0; c < CIN; ++c) xv[c] = xb[c * SP + q];
                    const float* wp = w + (kf + k4) * CIN;
                    #pragma unroll
                    for (int o = 0; o < COUT; ++o)
                        #pragma unroll
                        for (int c = 0; c < CIN; ++c)
                            acc[o] = fmaf(xv[c], wp[o * KW + c], acc[o]);
                }
            }
        }
    }
    float* ob = out + (size_t)b * COUT * SP + p;
    #pragma unroll
    for (int o = 0; o < COUT; ++o) ob[o * SP] = acc[o];
}

extern "C" void kernel_launch(void* const* d_in, const int* in_sizes, int n_in,
                              void* d_out, int out_size, void* d_ws, size_t ws_size,
                              hipStream_t stream)
{
    const float* x    = (const float*)d_in[0];
    const float* w    = (const float*)d_in[1];
    const float* bias = (const float*)d_in[2];
    float* out        = (float*)d_out;
    unsigned char* ws = (unsigned char*)d_ws;

    if (ws_size >= WS_NEEDED_PAD) {
        // padded fast path
        hipLaunchKernelGGL(prep0_pad, dim3(ZBLOCKS + 6), dim3(256), 0, stream, w, ws);
        hipLaunchKernelGGL(transpose_xp, dim3(BATCH * SP / 4 / 256), dim3(256), 0, stream,
                           x, ws);
        hipLaunchKernelGGL(conv4d_mfma_pad, dim3(NBLOCKS), dim3(256), 0, stream,
                           (const unsigned char*)ws, bias, out);
        return;
    }

    if (ws_size >= WS_NEEDED_OLD) {
        // old unpadded path
        hipLaunchKernelGGL(pack_weights, dim3(6), dim3(256), 0, stream, w, ws);
        const int pair_total = BATCH * SP / 2;
        hipLaunchKernelGGL(transpose_x, dim3(pair_total / 256), dim3(256), 0, stream, x, ws);
        hipLaunchKernelGGL(conv4d_mfma, dim3(NBLOCKS), dim3(256), 0, stream,
                           (const unsigned char*)ws, bias, out);
        return;
    }

    // insurance
    const int total = BATCH * SP;
    hipLaunchKernelGGL(conv4d_direct, dim3(total / 256), dim3(256), 0, stream,
                       x, w, bias, out);
}